// Round 2
// baseline (3375.547 us; speedup 1.0000x reference)
//
#include <hip/hip_runtime.h>
#include <math.h>

#define EPSV 1e-4f
#define NSWEEP 10
#define NP 101

// ---------- Kernel A: W = W1 @ W2 (400x200 @ 200x100 -> 400x100) ----------
__global__ __launch_bounds__(256) void kA(const float* __restrict__ W1,
                                          const float* __restrict__ W2,
                                          float* __restrict__ W) {
  int e = blockIdx.x * 256 + threadIdx.x;
  if (e >= 400 * 100) return;
  int i = e / 100, j = e - (e / 100) * 100;
  float s = 0.f;
#pragma unroll 4
  for (int k = 0; k < 200; ++k) s += W1[i * 200 + k] * W2[k * 100 + j];
  W[e] = s;
}

// ---------- Kernel B: Y[b] = x[b] @ W  (400x400 @ 400x100) ----------
__global__ __launch_bounds__(256) void kB(const float* __restrict__ x,
                                          const float* __restrict__ W,
                                          float* __restrict__ Y) {
  __shared__ float xs[16][41];
  __shared__ float ws[40][104];
  const int b = blockIdx.y, rt = blockIdx.x;
  const int tid = threadIdx.x;
  const int tc = tid & 31, tr = tid >> 5;
  const float* xb = x + (size_t)b * 160000 + (size_t)rt * 16 * 400;
  float acc[2][4] = {{0.f, 0.f, 0.f, 0.f}, {0.f, 0.f, 0.f, 0.f}};
  for (int k0 = 0; k0 < 400; k0 += 40) {
    for (int e = tid; e < 640; e += 256) {
      int r = e / 40, kk = e - r * 40;
      xs[r][kk] = xb[r * 400 + k0 + kk];
    }
    for (int e = tid; e < 4000; e += 256) {
      int kk = e / 100, j = e - kk * 100;
      ws[kk][j] = W[(k0 + kk) * 100 + j];
    }
    __syncthreads();
#pragma unroll 8
    for (int kk = 0; kk < 40; ++kk) {
      float a0 = xs[tr][kk], a1 = xs[tr + 8][kk];
      float b0 = ws[kk][tc], b1 = ws[kk][tc + 32], b2 = ws[kk][tc + 64];
      float b3 = (tc + 96 < 100) ? ws[kk][tc + 96] : 0.f;
      acc[0][0] += a0 * b0; acc[0][1] += a0 * b1; acc[0][2] += a0 * b2; acc[0][3] += a0 * b3;
      acc[1][0] += a1 * b0; acc[1][1] += a1 * b1; acc[1][2] += a1 * b2; acc[1][3] += a1 * b3;
    }
    __syncthreads();
  }
  float* Yb = Y + (size_t)b * 40000 + (size_t)rt * 1600;
#pragma unroll
  for (int rr = 0; rr < 2; ++rr) {
    int r = tr + 8 * rr;
#pragma unroll
    for (int u = 0; u < 4; ++u) {
      int c = tc + 32 * u;
      if (c < 100) Yb[r * 100 + c] = acc[rr][u];
    }
  }
}

// map flat triu index e (row-major upper triangle, r=100) -> row i
__device__ __forceinline__ int triu_row(int e) {
  int i = (int)((201.0f - sqrtf(40401.0f - 8.0f * (float)e)) * 0.5f);
  if (i < 0) i = 0;
  if (i > 99) i = 99;
  while (i > 0 && (201 * i - i * i) > 2 * e) --i;
  while ((201 * (i + 1) - (i + 1) * (i + 1)) <= 2 * e) ++i;
  return i;
}

// ---------- Kernel C: per-batch  M = W^T Y_b ; logm via Jacobi ; classifier ----------
__global__ __launch_bounds__(1024) void kC(const float* __restrict__ W,
                                           const float* __restrict__ Y,
                                           const float* __restrict__ Wc,
                                           const float* __restrict__ bcv,
                                           float* __restrict__ out) {
  __shared__ float A[100 * NP];
  __shared__ float V[100 * NP];
  __shared__ float cs_c[50], cs_s[50];
  __shared__ int cs_p[50], cs_q[50];
  __shared__ float lvec[100];
  __shared__ float red[16][12];

  const int b = blockIdx.x, tid = threadIdx.x;
  const int q4 = tid & 31;   // column base
  const int r32 = tid >> 5;  // row group in [0,32)

  // ---- M = W^T @ Y_b  into A (stage chunks through V's storage) ----
  // K-chunk = 40 (divides 400 exactly; the old 32 ran 16 rows OOB past W and Y_b)
  {
    float* Wst = V;           // [40][104]
    float* Yst = V + 4160;    // [40][104]
    const float* Yb = Y + (size_t)b * 40000;
    float acc[4][4];
#pragma unroll
    for (int m = 0; m < 4; ++m) acc[m][0] = acc[m][1] = acc[m][2] = acc[m][3] = 0.f;
    for (int k0 = 0; k0 < 400; k0 += 40) {
      for (int e = tid; e < 4000; e += 1024) {
        int kk = e / 100, j = e - kk * 100;
        Wst[kk * 104 + j] = W[(k0 + kk) * 100 + j];
        Yst[kk * 104 + j] = Yb[(k0 + kk) * 100 + j];
      }
      __syncthreads();
      for (int kk = 0; kk < 40; ++kk) {
        float y0 = Yst[kk * 104 + q4], y1 = Yst[kk * 104 + q4 + 32], y2 = Yst[kk * 104 + q4 + 64];
        float y3 = (q4 + 96 < 100) ? Yst[kk * 104 + q4 + 96] : 0.f;
#pragma unroll
        for (int m = 0; m < 4; ++m) {
          int p = r32 + 32 * m;
          if (p < 100) {
            float w = Wst[kk * 104 + p];
            acc[m][0] += w * y0; acc[m][1] += w * y1; acc[m][2] += w * y2; acc[m][3] += w * y3;
          }
        }
      }
      __syncthreads();
    }
#pragma unroll
    for (int m = 0; m < 4; ++m) {
      int p = r32 + 32 * m;
      if (p < 100) {
        A[p * NP + q4] = acc[m][0];
        A[p * NP + q4 + 32] = acc[m][1];
        A[p * NP + q4 + 64] = acc[m][2];
        if (q4 + 96 < 100) A[p * NP + q4 + 96] = acc[m][3];
      }
    }
  }
  // V = I (staging no longer needed)
  for (int e = tid; e < 100 * NP; e += 1024) {
    int r = e / NP, c = e - r * NP;
    V[e] = (r == c) ? 1.f : 0.f;
  }
  __syncthreads();
  // symmetrize A (kills fp asymmetry from the two GEMMs)
  for (int e = tid; e < 5050; e += 1024) {
    int i = triu_row(e);
    int j = i + (e - ((201 * i - i * i) >> 1));
    float av = 0.5f * (A[i * NP + j] + A[j * NP + i]);
    A[i * NP + j] = av;
    A[j * NP + i] = av;
  }
  __syncthreads();

  // ---- cyclic Jacobi: NSWEEP sweeps of 99 rounds x 50 disjoint pairs ----
  for (int sw = 0; sw < NSWEEP; ++sw) {
    for (int r = 0; r < 99; ++r) {
      if (tid < 50) {
        int p, q;
        if (tid == 0) {
          p = 99; q = r;
        } else {
          p = r + tid; if (p >= 99) p -= 99;
          q = r - tid; if (q < 0) q += 99;
        }
        float app = A[p * NP + p], aqq = A[q * NP + q], apq = A[p * NP + q];
        float c = 1.f, s = 0.f;
        if (apq * apq > 1e-12f * fabsf(app * aqq) + 1e-30f) {
          float tau = (aqq - app) / (2.f * apq);
          float t = copysignf(1.f, tau) / (fabsf(tau) + sqrtf(1.f + tau * tau));
          c = 1.f / sqrtf(1.f + t * t);
          s = t * c;
        }
        cs_c[tid] = c; cs_s[tid] = s; cs_p[tid] = p; cs_q[tid] = q;
      }
      __syncthreads();
      // row phase: A <- J^T A
      for (int e = tid; e < 5000; e += 1024) {
        int pr = e / 100, k = e - pr * 100;
        float s = cs_s[pr];
        if (s != 0.f) {
          float c = cs_c[pr];
          int p = cs_p[pr], q = cs_q[pr];
          float ap = A[p * NP + k], aq = A[q * NP + k];
          A[p * NP + k] = c * ap - s * aq;
          A[q * NP + k] = s * ap + c * aq;
        }
      }
      __syncthreads();
      // col phase: A <- A J ; and V <- V J
      for (int e = tid; e < 10000; e += 1024) {
        int e2 = (e < 5000) ? e : e - 5000;
        int pr = e2 / 100, k = e2 - pr * 100;
        float s = cs_s[pr];
        if (s != 0.f) {
          float c = cs_c[pr];
          int p = cs_p[pr], q = cs_q[pr];
          if (e < 5000) {
            float ap = A[k * NP + p], aq = A[k * NP + q];
            A[k * NP + p] = c * ap - s * aq;
            A[k * NP + q] = s * ap + c * aq;
          } else {
            float vp = V[k * NP + p], vq = V[k * NP + q];
            V[k * NP + p] = c * vp - s * vq;
            V[k * NP + q] = s * vp + c * vq;
          }
        }
      }
      __syncthreads();
    }
  }

  // ---- eigenvalue log ----
  for (int i2 = tid; i2 < 100; i2 += 1024) lvec[i2] = logf(fmaxf(A[i2 * NP + i2], EPSV));
  __syncthreads();

  // ---- H = V diag(lvec) V^T  into A ----
  {
    float hacc[4][4];
#pragma unroll
    for (int m = 0; m < 4; ++m) hacc[m][0] = hacc[m][1] = hacc[m][2] = hacc[m][3] = 0.f;
    for (int p = 0; p < 100; ++p) {
      float l = lvec[p];
      float vj0 = V[q4 * NP + p], vj1 = V[(q4 + 32) * NP + p], vj2 = V[(q4 + 64) * NP + p];
      float vj3 = (q4 + 96 < 100) ? V[(q4 + 96) * NP + p] : 0.f;
#pragma unroll
      for (int m = 0; m < 4; ++m) {
        int i = r32 + 32 * m;
        if (i < 100) {
          float vil = V[i * NP + p] * l;
          hacc[m][0] += vil * vj0; hacc[m][1] += vil * vj1;
          hacc[m][2] += vil * vj2; hacc[m][3] += vil * vj3;
        }
      }
    }
    __syncthreads();
#pragma unroll
    for (int m = 0; m < 4; ++m) {
      int i = r32 + 32 * m;
      if (i < 100) {
        A[i * NP + q4] = hacc[m][0];
        A[i * NP + q4 + 32] = hacc[m][1];
        A[i * NP + q4 + 64] = hacc[m][2];
        if (q4 + 96 < 100) A[i * NP + q4 + 96] = hacc[m][3];
      }
    }
  }
  __syncthreads();

  // ---- classifier: out[b][c] = bc[c] + sum_triu H[i][j] * Wc[c][e] ----
  float accc[10];
#pragma unroll
  for (int c = 0; c < 10; ++c) accc[c] = 0.f;
  for (int e = tid; e < 5050; e += 1024) {
    int i = triu_row(e);
    int j = i + (e - ((201 * i - i * i) >> 1));
    float h = A[i * NP + j];
#pragma unroll
    for (int c = 0; c < 10; ++c) accc[c] += h * Wc[c * 5050 + e];
  }
  const int lane = tid & 63, wv = tid >> 6;
#pragma unroll
  for (int c = 0; c < 10; ++c) {
    float v = accc[c];
#pragma unroll
    for (int off = 32; off > 0; off >>= 1) v += __shfl_down(v, off);
    if (lane == 0) red[wv][c] = v;
  }
  __syncthreads();
  if (tid < 10) {
    float s = bcv[tid];
#pragma unroll
    for (int w = 0; w < 16; ++w) s += red[w][tid];
    out[b * 10 + tid] = s;
  }
}

extern "C" void kernel_launch(void* const* d_in, const int* in_sizes, int n_in,
                              void* d_out, int out_size, void* d_ws, size_t ws_size,
                              hipStream_t stream) {
  const float* x = (const float*)d_in[0];
  const float* W1 = (const float*)d_in[1];
  const float* W2 = (const float*)d_in[2];
  const float* Wc = (const float*)d_in[3];
  const float* bc = (const float*)d_in[4];
  float* out = (float*)d_out;

  float* W = (float*)d_ws;        // 400*100 floats
  float* Y = W + 40000;           // 256*400*100 floats (~41 MB)

  kA<<<157, 256, 0, stream>>>(W1, W2, W);
  kB<<<dim3(25, 256), 256, 0, stream>>>(x, W, Y);
  kC<<<256, 1024, 0, stream>>>(W, Y, Wc, bc, out);
}

// Round 3
// 1795.054 us; speedup vs baseline: 1.8805x; 1.8805x over previous
//
#include <hip/hip_runtime.h>
#include <math.h>

#define EPSV 1e-4f
#define NSWEEP 10
#define NP 104   // row pitch: 104*4B = 416B, 16B-aligned so float4 LDS ops are legal

// ---------- Kernel A: W = W1 @ W2 (400x200 @ 200x100 -> 400x100) ----------
__global__ __launch_bounds__(256) void kA(const float* __restrict__ W1,
                                          const float* __restrict__ W2,
                                          float* __restrict__ W) {
  int e = blockIdx.x * 256 + threadIdx.x;
  if (e >= 400 * 100) return;
  int i = e / 100, j = e - (e / 100) * 100;
  float s = 0.f;
#pragma unroll 4
  for (int k = 0; k < 200; ++k) s += W1[i * 200 + k] * W2[k * 100 + j];
  W[e] = s;
}

// ---------- Kernel B: Y[b] = x[b] @ W  (400x400 @ 400x100) ----------
__global__ __launch_bounds__(256) void kB(const float* __restrict__ x,
                                          const float* __restrict__ W,
                                          float* __restrict__ Y) {
  __shared__ float xs[16][41];
  __shared__ float ws[40][104];
  const int b = blockIdx.y, rt = blockIdx.x;
  const int tid = threadIdx.x;
  const int tc = tid & 31, tr = tid >> 5;
  const float* xb = x + (size_t)b * 160000 + (size_t)rt * 16 * 400;
  float acc[2][4] = {{0.f, 0.f, 0.f, 0.f}, {0.f, 0.f, 0.f, 0.f}};
  for (int k0 = 0; k0 < 400; k0 += 40) {
    for (int e = tid; e < 640; e += 256) {
      int r = e / 40, kk = e - r * 40;
      xs[r][kk] = xb[r * 400 + k0 + kk];
    }
    for (int e = tid; e < 4000; e += 256) {
      int kk = e / 100, j = e - kk * 100;
      ws[kk][j] = W[(k0 + kk) * 100 + j];
    }
    __syncthreads();
#pragma unroll 8
    for (int kk = 0; kk < 40; ++kk) {
      float a0 = xs[tr][kk], a1 = xs[tr + 8][kk];
      float b0 = ws[kk][tc], b1 = ws[kk][tc + 32], b2 = ws[kk][tc + 64];
      float b3 = (tc + 96 < 100) ? ws[kk][tc + 96] : 0.f;
      acc[0][0] += a0 * b0; acc[0][1] += a0 * b1; acc[0][2] += a0 * b2; acc[0][3] += a0 * b3;
      acc[1][0] += a1 * b0; acc[1][1] += a1 * b1; acc[1][2] += a1 * b2; acc[1][3] += a1 * b3;
    }
    __syncthreads();
  }
  float* Yb = Y + (size_t)b * 40000 + (size_t)rt * 1600;
#pragma unroll
  for (int rr = 0; rr < 2; ++rr) {
    int r = tr + 8 * rr;
#pragma unroll
    for (int u = 0; u < 4; ++u) {
      int c = tc + 32 * u;
      if (c < 100) Yb[r * 100 + c] = acc[rr][u];
    }
  }
}

// map flat triu index e (row-major upper triangle, r=100) -> row i
__device__ __forceinline__ int triu_row(int e) {
  int i = (int)((201.0f - sqrtf(40401.0f - 8.0f * (float)e)) * 0.5f);
  if (i < 0) i = 0;
  if (i > 99) i = 99;
  while (i > 0 && (201 * i - i * i) > 2 * e) --i;
  while ((201 * (i + 1) - (i + 1) * (i + 1)) <= 2 * e) ++i;
  return i;
}

// ---------- Kernel C: per-batch  M = W^T Y_b ; logm via Jacobi ; classifier ----------
__global__ __launch_bounds__(1024) void kC(const float* __restrict__ W,
                                           const float* __restrict__ Y,
                                           const float* __restrict__ Wc,
                                           const float* __restrict__ bcv,
                                           float* __restrict__ out) {
  __shared__ float A[100 * NP];
  __shared__ float Vt[100 * NP];   // stores V^T: rows of Vt are columns of V
  __shared__ float cs_c[50], cs_s[50];
  __shared__ int cs_p[50], cs_q[50];
  __shared__ float lvec[100];
  __shared__ float red[16][12];
  __shared__ int anyrot[NSWEEP];

  const int b = blockIdx.x, tid = threadIdx.x;
  const int q4 = tid & 31;   // column base
  const int r32 = tid >> 5;  // row group in [0,32)

  // ---- M = W^T @ Y_b  into A (stage K-chunks of 40 through Vt's storage) ----
  {
    float* Wst = Vt;          // [40][104]
    float* Yst = Vt + 4160;   // [40][104]
    const float* Yb = Y + (size_t)b * 40000;
    float acc[4][4];
#pragma unroll
    for (int m = 0; m < 4; ++m) acc[m][0] = acc[m][1] = acc[m][2] = acc[m][3] = 0.f;
    for (int k0 = 0; k0 < 400; k0 += 40) {
      for (int e = tid; e < 4000; e += 1024) {
        int kk = e / 100, j = e - kk * 100;
        Wst[kk * 104 + j] = W[(k0 + kk) * 100 + j];
        Yst[kk * 104 + j] = Yb[(k0 + kk) * 100 + j];
      }
      __syncthreads();
      for (int kk = 0; kk < 40; ++kk) {
        float y0 = Yst[kk * 104 + q4], y1 = Yst[kk * 104 + q4 + 32], y2 = Yst[kk * 104 + q4 + 64];
        float y3 = (q4 + 96 < 100) ? Yst[kk * 104 + q4 + 96] : 0.f;
#pragma unroll
        for (int m = 0; m < 4; ++m) {
          int p = r32 + 32 * m;
          if (p < 100) {
            float w = Wst[kk * 104 + p];
            acc[m][0] += w * y0; acc[m][1] += w * y1; acc[m][2] += w * y2; acc[m][3] += w * y3;
          }
        }
      }
      __syncthreads();
    }
#pragma unroll
    for (int m = 0; m < 4; ++m) {
      int p = r32 + 32 * m;
      if (p < 100) {
        A[p * NP + q4] = acc[m][0];
        A[p * NP + q4 + 32] = acc[m][1];
        A[p * NP + q4 + 64] = acc[m][2];
        if (q4 + 96 < 100) A[p * NP + q4 + 96] = acc[m][3];
      }
    }
  }
  // Vt = I (staging storage no longer needed); clear sweep flags
  for (int e = tid; e < 100 * NP; e += 1024) {
    int r = e / NP, c = e - r * NP;
    Vt[e] = (r == c) ? 1.f : 0.f;
  }
  if (tid < NSWEEP) anyrot[tid] = 0;
  __syncthreads();
  // symmetrize A (kills fp asymmetry from the two GEMMs)
  for (int e = tid; e < 5050; e += 1024) {
    int i = triu_row(e);
    int j = i + (e - ((201 * i - i * i) >> 1));
    float av = 0.5f * (A[i * NP + j] + A[j * NP + i]);
    A[i * NP + j] = av;
    A[j * NP + i] = av;
  }
  __syncthreads();

  // ---- cyclic Jacobi: sweeps of 99 rounds x 50 disjoint pairs ----
  // Per round: A' = G A G^T done as 2500 independent 2x2 blocks (pairs
  // partition indices -> each element belongs to exactly one block: no hazard,
  // single phase, 2 barriers/round). Vt' = G Vt: row-contiguous, float4.
  for (int sw = 0; sw < NSWEEP; ++sw) {
    for (int r = 0; r < 99; ++r) {
      if (tid < 50) {
        int p, q;
        if (tid == 0) {
          p = 99; q = r;
        } else {
          p = r + tid; if (p >= 99) p -= 99;
          q = r - tid; if (q < 0) q += 99;
        }
        float app = A[p * NP + p], aqq = A[q * NP + q], apq = A[p * NP + q];
        float c = 1.f, s = 0.f;
        if (apq * apq > 1e-12f * fabsf(app * aqq) + 1e-30f) {
          float tau = (aqq - app) / (2.f * apq);
          float t = copysignf(1.f, tau) / (fabsf(tau) + sqrtf(1.f + tau * tau));
          c = 1.f / sqrtf(1.f + t * t);
          s = t * c;
          anyrot[sw] = 1;
        }
        cs_c[tid] = c; cs_s[tid] = s; cs_p[tid] = p; cs_q[tid] = q;
      }
      __syncthreads();
      // A: 2500 disjoint 2x2 block updates  A'[Ia,Ib] = Ga * A[Ia,Ib] * Gb^T
      for (int e = tid; e < 2500; e += 1024) {
        int a = e / 50, bq = e - a * 50;
        float sa = cs_s[a], sb = cs_s[bq];
        if (sa != 0.f || sb != 0.f) {
          float ca = cs_c[a], cb = cs_c[bq];
          int pb = cs_p[bq], qb = cs_q[bq];
          float* rp = A + cs_p[a] * NP;
          float* rq = A + cs_q[a] * NP;
          float m00 = rp[pb], m01 = rp[qb], m10 = rq[pb], m11 = rq[qb];
          float t00 = ca * m00 - sa * m10;
          float t01 = ca * m01 - sa * m11;
          float t10 = sa * m00 + ca * m10;
          float t11 = sa * m01 + ca * m11;
          rp[pb] = cb * t00 - sb * t01;
          rp[qb] = sb * t00 + cb * t01;
          rq[pb] = cb * t10 - sb * t11;
          rq[qb] = sb * t10 + cb * t11;
        }
      }
      // Vt: rows p,q mixed, float4-contiguous (25 float4 per row)
      for (int e = tid; e < 1250; e += 1024) {
        int pr = e / 25, k4 = (e - pr * 25) << 2;
        float s = cs_s[pr];
        if (s != 0.f) {
          float c = cs_c[pr];
          float4* vp = (float4*)&Vt[cs_p[pr] * NP + k4];
          float4* vq = (float4*)&Vt[cs_q[pr] * NP + k4];
          float4 a4 = *vp, b4 = *vq, n4, m4;
          n4.x = c * a4.x - s * b4.x; n4.y = c * a4.y - s * b4.y;
          n4.z = c * a4.z - s * b4.z; n4.w = c * a4.w - s * b4.w;
          m4.x = s * a4.x + c * b4.x; m4.y = s * a4.y + c * b4.y;
          m4.z = s * a4.z + c * b4.z; m4.w = s * a4.w + c * b4.w;
          *vp = n4; *vq = m4;
        }
      }
      __syncthreads();
    }
    if (anyrot[sw] == 0) break;  // whole sweep rotation-free -> converged
  }

  // ---- eigenvalue log ----
  for (int i2 = tid; i2 < 100; i2 += 1024) lvec[i2] = logf(fmaxf(A[i2 * NP + i2], EPSV));
  __syncthreads();

  // ---- H = sum_p l_p * Vt[p][i] * Vt[p][j]  into A ----
  {
    float hacc[4][4];
#pragma unroll
    for (int m = 0; m < 4; ++m) hacc[m][0] = hacc[m][1] = hacc[m][2] = hacc[m][3] = 0.f;
    for (int p = 0; p < 100; ++p) {
      float l = lvec[p];
      const float* vr = Vt + p * NP;
      float vj0 = vr[q4], vj1 = vr[q4 + 32], vj2 = vr[q4 + 64];
      float vj3 = (q4 + 96 < 100) ? vr[q4 + 96] : 0.f;
#pragma unroll
      for (int m = 0; m < 4; ++m) {
        int i = r32 + 32 * m;
        if (i < 100) {
          float vil = vr[i] * l;
          hacc[m][0] += vil * vj0; hacc[m][1] += vil * vj1;
          hacc[m][2] += vil * vj2; hacc[m][3] += vil * vj3;
        }
      }
    }
    __syncthreads();
#pragma unroll
    for (int m = 0; m < 4; ++m) {
      int i = r32 + 32 * m;
      if (i < 100) {
        A[i * NP + q4] = hacc[m][0];
        A[i * NP + q4 + 32] = hacc[m][1];
        A[i * NP + q4 + 64] = hacc[m][2];
        if (q4 + 96 < 100) A[i * NP + q4 + 96] = hacc[m][3];
      }
    }
  }
  __syncthreads();

  // ---- classifier: out[b][c] = bc[c] + sum_triu H[i][j] * Wc[c][e] ----
  float accc[10];
#pragma unroll
  for (int c = 0; c < 10; ++c) accc[c] = 0.f;
  for (int e = tid; e < 5050; e += 1024) {
    int i = triu_row(e);
    int j = i + (e - ((201 * i - i * i) >> 1));
    float h = A[i * NP + j];
#pragma unroll
    for (int c = 0; c < 10; ++c) accc[c] += h * Wc[c * 5050 + e];
  }
  const int lane = tid & 63, wv = tid >> 6;
#pragma unroll
  for (int c = 0; c < 10; ++c) {
    float v = accc[c];
#pragma unroll
    for (int off = 32; off > 0; off >>= 1) v += __shfl_down(v, off);
    if (lane == 0) red[wv][c] = v;
  }
  __syncthreads();
  if (tid < 10) {
    float s = bcv[tid];
#pragma unroll
    for (int w = 0; w < 16; ++w) s += red[w][tid];
    out[b * 10 + tid] = s;
  }
}

extern "C" void kernel_launch(void* const* d_in, const int* in_sizes, int n_in,
                              void* d_out, int out_size, void* d_ws, size_t ws_size,
                              hipStream_t stream) {
  const float* x = (const float*)d_in[0];
  const float* W1 = (const float*)d_in[1];
  const float* W2 = (const float*)d_in[2];
  const float* Wc = (const float*)d_in[3];
  const float* bc = (const float*)d_in[4];
  float* out = (float*)d_out;

  float* W = (float*)d_ws;        // 400*100 floats
  float* Y = W + 40000;           // 256*400*100 floats (~41 MB)

  kA<<<157, 256, 0, stream>>>(W1, W2, W);
  kB<<<dim3(25, 256), 256, 0, stream>>>(x, W, Y);
  kC<<<256, 1024, 0, stream>>>(W, Y, Wc, bc, out);
}